// Round 10
// baseline (82.929 us; speedup 1.0000x reference)
//
#include <hip/hip_runtime.h>
#include <hip/hip_bf16.h>
#include <cstddef>
#include <cstdint>

typedef __attribute__((ext_vector_type(8))) short short8_t;   // 8 bf16 (4 VGPRs)
typedef __attribute__((ext_vector_type(4))) float f32x4;
typedef __attribute__((ext_vector_type(2))) float f32x2;
typedef unsigned short ushort4a __attribute__((ext_vector_type(4))); // 8B

// Per-wave fences: forbid compiler motion of memory ops and drain the HW
// queue. Cross-lane LDS deps and LDS-DMA writes are invisible to per-thread
// dependence analysis.
#define WAVE_FENCE()                                        \
  do {                                                      \
    asm volatile("s_waitcnt lgkmcnt(0)" ::: "memory");      \
    __builtin_amdgcn_sched_barrier(0);                      \
  } while (0)
#define VM_FENCE()                                          \
  do {                                                      \
    asm volatile("s_waitcnt vmcnt(0)" ::: "memory");        \
    __builtin_amdgcn_sched_barrier(0);                      \
  } while (0)
// R22: counted wait -- current tile's 4 LDS-DMA loads retired, next tile's 4
// may remain in flight. Valid only because DMA issues are pinned oldest in
// the VMEM queue (sched_barrier after prologue issues; loop body has no other
// VMEM ops).
#define VM_WAIT4()                                          \
  do {                                                      \
    asm volatile("s_waitcnt vmcnt(4)" ::: "memory");        \
    __builtin_amdgcn_sched_barrier(0);                      \
  } while (0)

namespace {
constexpr int T = 2048;
constexpr int NB = 16;
constexpr int NJ = 53;
constexpr int NN = 18;              // names
constexpr int TTILE = 256;          // R16: per-block tax amortization; NT stores keep L2 reuse
constexpr int NTILES = T / TTILE;   // 8
constexpr int MT_LIN = 17;          // ceil(258/16) m-tiles for linear phase
constexpr int MT_CNV = 16;          // conv m-tiles
constexpr int HROWS = TTILE + 2;    // 258 h rows actually consumed by conv
constexpr int HSTR = 36;            // ushort stride per h row (72B, 8B-aligned rows)
// SSTR=38 (R15): g-stride 152B == 24 mod 32 dwords -> staging writes 2-way (free).
constexpr int SSTR = 38;            // f32 stride of store-staging tile (152B)
constexpr int NBLK = NB * NJ * NTILES;  // 6784
constexpr int XSPAN = NBLK / 8;         // 848 (bijective XCD swizzle)
}

__constant__ int c_name_ids[NJ] = {
    0,1,2,3,4,1,2,3,4,5,6,7,8,9,10,11,12,13,14,15,16,14,15,16,14,15,16,
    14,15,16,14,15,16,10,11,12,13,14,15,16,14,15,16,14,15,16,14,15,16,
    14,15,16,17};

// Precomputed weight fragments: [name][ks|k][nt][hi/lo][lane]
__device__ short8_t g_linfrag[NN][2][2][2][64];   // 147 KB
__device__ short8_t g_convfrag[NN][3][2][2][64];  // 221 KB

__device__ __forceinline__ unsigned short f2bf(float f) {
  return __builtin_bit_cast(unsigned short, __float2bfloat16(f));
}
__device__ __forceinline__ float bf2f(unsigned short u) {
  return __bfloat162float(__builtin_bit_cast(__hip_bfloat16, u));
}

// slot map: slot(g,e) -> k = 4g + (e&3) + 16*(e>>2); used identically for A and B
// fragments, so any true HW k-map yields a correct dot product.

__global__ __launch_bounds__(64)
void prep_weights(const float* __restrict__ lin_w,
                  const float* __restrict__ conv_w)
{
  const int n = blockIdx.x;
  const int l = threadIdx.x;
  const int r = l & 15;
  const int g = l >> 4;
#pragma unroll
  for (int ks = 0; ks < 2; ++ks)
#pragma unroll
    for (int nt = 0; nt < 2; ++nt) {
      short8_t hi8, lo8;
#pragma unroll
      for (int e = 0; e < 8; ++e) {
        const int kk = 4 * g + (e & 3) + 16 * (e >> 2);
        const float w = lin_w[((size_t)n * 64 + ks * 32 + kk) * 32 + r + 16 * nt];
        const unsigned short h = f2bf(w);
        hi8[e] = (short)h;
        lo8[e] = (short)f2bf(w - bf2f(h));
      }
      g_linfrag[n][ks][nt][0][l] = hi8;
      g_linfrag[n][ks][nt][1][l] = lo8;
    }
#pragma unroll
  for (int k = 0; k < 3; ++k)
#pragma unroll
    for (int nt = 0; nt < 2; ++nt) {
      short8_t hi8, lo8;
#pragma unroll
      for (int e = 0; e < 8; ++e) {
        const int i = 4 * g + (e & 3) + 16 * (e >> 2);
        const float w = conv_w[(((size_t)n * 32 + r + 16 * nt) * 32 + i) * 3 + k];
        const unsigned short h = f2bf(w);
        hi8[e] = (short)h;
        lo8[e] = (short)f2bf(w - bf2f(h));
      }
      g_convfrag[n][k][nt][0][l] = hi8;
      g_convfrag[n][k][nt][1][l] = lo8;
    }
}

// R22 = R21 + DEPTH-2 double-buffered feat staging with counted vmcnt.
// R21's result proved the cvt chain wasn't critical (VALUBusy -6pts, dur
// unchanged); the only remaining consumer is waitcnt stall: each lin iter
// drained vmcnt(0) with ~1 short iteration of cover vs 200-900cy L2/HBM
// latency. Now: prologue issues tiles wv,wv+4 into buf0/buf1; loop head
// waits vmcnt(4) (current landed, next in flight); after fragment reads
// retire, issue tile mt+8 into the freed buffer. Issue->wait distance = 2
// full iterations (~600+cy). Last-iter peel waits vmcnt(0).
// Cost: LDS 35.3 -> 51.3KB -> 3 blocks/CU (12 waves vs 16). R20 proved more
// waves don't help; betting fewer non-stalling waves beat more stalling ones.
// Kept: R21 dropped input-residual, SSTR=38, NT stores, LDS-DMA transport,
// phase separation, (256,4) launch bounds.
__global__ __launch_bounds__(256, 4)
void fused_rcb_mfma(const float* __restrict__ x,
                    const float* __restrict__ lin_b,
                    const float* __restrict__ conv_b,
                    float* __restrict__ out)
{
  __shared__ __align__(16) unsigned short s_hi[HROWS * HSTR];  // 18.6 KB
  __shared__ __align__(16) char s_feat[4][2][4096];            // 32 KB: 2-deep feat ring / store stage (conv)

  const int raw = blockIdx.x;
  const int bid = (raw % 8) * XSPAN + (raw / 8);   // bijective XCD swizzle
  const int j    = bid % NJ;
  const int tile = (bid / NJ) % NTILES;
  const int b    = bid / (NJ * NTILES);
  const int nid  = c_name_ids[j];
  const int jp   = (j > 0) ? (j - 1) : 0;
  const int t0   = tile * TTILE;

  const int tid = threadIdx.x;
  const int wv = tid >> 6;        // wave 0..3
  const int l  = tid & 63;
  const int r  = l & 15;          // M/N index within fragment
  const int g  = l >> 4;          // k-slot group

  const float* xj_base = x + ((size_t)b * T * NJ + j) * 32;
  const float* xp_base = x + ((size_t)b * T * NJ + jp) * 32;

  // Issue the 4 LDS-DMA loads for m-tile mt into ring slot p. Each
  // instruction is a contiguous 1KB (8 full lines); global source byte is
  // inverse-XOR-swizzled so LDS holds the swizzled layout (rule #21).
  auto issue_feat = [&](int mt, int p) {
#pragma unroll
    for (int j2 = 0; j2 < 2; ++j2) {
      const float* jb = j2 ? xp_base : xj_base;
#pragma unroll
      for (int i = 0; i < 2; ++i) {
        const int row = i * 8 + (l >> 3);
        int t = t0 + mt * 16 + row - 1;       // reflect padding in time
        if (t < 0) t = -t;
        if (t > T - 1) t = 2 * (T - 1) - t;
        const char* src = reinterpret_cast<const char*>(jb + (size_t)t * (NJ * 32))
                          + (((l & 7) * 16) ^ ((row & 7) << 4));
        __builtin_amdgcn_global_load_lds(
            (const __attribute__((address_space(1))) unsigned int*)src,
            (__attribute__((address_space(3))) unsigned int*)(&s_feat[wv][p][j2 * 2048 + i * 1024]),
            16, 0, 0);
      }
    }
  };

  // ---- prologue: DMA issues FIRST (pinned oldest in VMEM queue), then
  // weight loads. vmcnt(4) at the first loop head then provably covers the
  // 8 DMA ops (oldest); the compiler's own waits handle the weight regs.
  issue_feat(wv, 0);
  issue_feat(wv + 4, 1);          // wv+4 <= 7 < MT_LIN always
  __builtin_amdgcn_sched_barrier(0);

  // ---- linear weight fragments: coalesced 16B/lane loads from prep table ----
  short8_t blh[2][2], bll[2][2];
#pragma unroll
  for (int ks = 0; ks < 2; ++ks)
#pragma unroll
    for (int nt = 0; nt < 2; ++nt) {
      blh[ks][nt] = g_linfrag[nid][ks][nt][0][l];
      bll[ks][nt] = g_linfrag[nid][ks][nt][1][l];
    }
  const float lb0 = lin_b[nid * 32 + r];
  const float lb1 = lin_b[nid * 32 + r + 16];

  // ---------------- linear phase: h = relu(feat @ W + b) ----------------
  for (int mt = wv; mt < MT_LIN; mt += 4) {
    const int p = (mt >> 2) & 1;              // ring parity of this tile
    if (mt + 4 < MT_LIN) VM_WAIT4();          // current landed; next in flight
    else                 VM_FENCE();          // last tile: drain all

    // Fragment ds_reads; then free the buffer and refill it 2 tiles ahead.
    f32x4 a0[2], a1[2];
#pragma unroll
    for (int ks = 0; ks < 2; ++ks) {
      const char* fw = &s_feat[wv][p][ks * 2048 + r * 128];
      a0[ks] = *reinterpret_cast<const f32x4*>(fw + ((16 * g) ^ ((r & 7) << 4)));
      a1[ks] = *reinterpret_cast<const f32x4*>(fw + ((64 + 16 * g) ^ ((r & 7) << 4)));
    }
    WAVE_FENCE();                       // feat reads retired -> slot p reusable
    if (mt + 8 < MT_LIN) issue_feat(mt + 8, p);   // refill; waits 2 iters

    // R21: input hi-part only (RTZ top16); residual dropped (conv phase has
    // always dropped its input residual and passes).
    short8_t ah[2];
#pragma unroll
    for (int ks = 0; ks < 2; ++ks) {
#pragma unroll
      for (int e = 0; e < 8; ++e) {
        const float f = (e < 4) ? a0[ks][e] : a1[ks][e - 4];
        ah[ks][e] = (short)(unsigned short)(__builtin_bit_cast(uint32_t, f) >> 16);
      }
    }

#pragma unroll
    for (int nt = 0; nt < 2; ++nt) {
      const float lb = nt ? lb1 : lb0;
      f32x4 acc = {lb, lb, lb, lb};
#pragma unroll
      for (int ks = 0; ks < 2; ++ks) {
        acc = __builtin_amdgcn_mfma_f32_16x16x32_bf16(ah[ks], blh[ks][nt], acc, 0, 0, 0);
        acc = __builtin_amdgcn_mfma_f32_16x16x32_bf16(ah[ks], bll[ks][nt], acc, 0, 0, 0);
      }
      // C/D layout (m89): row = 4g+q, col = r
#pragma unroll
      for (int q = 0; q < 4; ++q) {
        const int hrow = mt * 16 + 4 * g + q;
        if (hrow < HROWS)   // only mt=16 tail rows are out of range
          s_hi[hrow * HSTR + r + 16 * nt] = f2bf(fmaxf(acc[q], 0.0f));
      }
    }
  }

  // ---- conv weight fragments: issue BEFORE the barrier so the global-load
  // latency hides under the slowest wave's lin tail ----
  short8_t bch[3][2], bcl[3][2];
#pragma unroll
  for (int k = 0; k < 3; ++k)
#pragma unroll
    for (int nt = 0; nt < 2; ++nt) {
      bch[k][nt] = g_convfrag[nid][k][nt][0][l];
      bcl[k][nt] = g_convfrag[nid][k][nt][1][l];
    }
  const float cb0 = conv_b[nid * 32 + r];
  const float cb1 = conv_b[nid * 32 + r + 16];

  __syncthreads();

  float* st = reinterpret_cast<float*>(&s_feat[wv][0][0]);  // alias: feat ring dead in conv

  // ---------------- conv phase: y[t] = sum_k h[t+k-1] @ cw[k] + cb ----------------
  for (int mt = wv; mt < MT_CNV; mt += 4) {
    const int m0 = mt * 16;
    short8_t ah[3];
#pragma unroll
    for (int k = 0; k < 3; ++k) {
      const int arow = m0 + r + k;
      const ushort4a u0 = *reinterpret_cast<const ushort4a*>(&s_hi[arow * HSTR + 4 * g]);
      const ushort4a u1 = *reinterpret_cast<const ushort4a*>(&s_hi[arow * HSTR + 16 + 4 * g]);
      short8_t hi8;
#pragma unroll
      for (int e = 0; e < 4; ++e) {
        hi8[e] = (short)u0[e];
        hi8[e + 4] = (short)u1[e];
      }
      ah[k] = hi8;
    }

    f32x4 accv[2];
#pragma unroll
    for (int nt = 0; nt < 2; ++nt) {
      const float cb = nt ? cb1 : cb0;
      f32x4 acc = {cb, cb, cb, cb};
#pragma unroll
      for (int k = 0; k < 3; ++k) {
        acc = __builtin_amdgcn_mfma_f32_16x16x32_bf16(ah[k], bch[k][nt], acc, 0, 0, 0);
        acc = __builtin_amdgcn_mfma_f32_16x16x32_bf16(ah[k], bcl[k][nt], acc, 0, 0, 0);
      }
      accv[nt] = acc;
    }

    // ---- wide-store epilogue: transpose acc through wave-private LDS ----
    WAVE_FENCE();   // WAR: previous m-tile's staging reads retired
#pragma unroll
    for (int nt = 0; nt < 2; ++nt)
#pragma unroll
      for (int q = 0; q < 4; ++q)
        st[(4 * g + q) * SSTR + r + 16 * nt] = accv[nt][q];
    WAVE_FENCE();   // RAW: staging writes visible to transposed reads

#pragma unroll
    for (int h2 = 0; h2 < 2; ++h2) {
      const int row = h2 * 8 + (l >> 3);          // 8-lane groups read one row
      const float* rp = st + row * SSTR + (l & 7) * 4;
      const f32x2 rd0 = *reinterpret_cast<const f32x2*>(rp);      // 8B reads keep
      const f32x2 rd1 = *reinterpret_cast<const f32x2*>(rp + 2);  // odd rows aligned
      f32x4 rd;
      rd[0] = rd0[0]; rd[1] = rd0[1]; rd[2] = rd1[0]; rd[3] = rd1[1];
      const int t = t0 + m0 + row;
      // Nontemporal: out is write-once; do not evict the L2-resident x columns.
      __builtin_nontemporal_store(rd, reinterpret_cast<f32x4*>(
          out + ((size_t)(b * T + t) * NJ + j) * 32 + (l & 7) * 4));
    }
  }
}

extern "C" void kernel_launch(void* const* d_in, const int* in_sizes, int n_in,
                              void* d_out, int out_size, void* d_ws, size_t ws_size,
                              hipStream_t stream) {
  const float* x      = (const float*)d_in[0];
  const float* lin_w  = (const float*)d_in[1];
  const float* lin_b  = (const float*)d_in[2];
  const float* conv_w = (const float*)d_in[3];
  const float* conv_b = (const float*)d_in[4];
  float* out = (float*)d_out;

  prep_weights<<<dim3(NN), 64, 0, stream>>>(lin_w, conv_w);
  fused_rcb_mfma<<<dim3(NBLK), 256, 0, stream>>>(x, lin_b, conv_b, out);
}